// Round 15
// baseline (89.110 us; speedup 1.0000x reference)
//
#include <hip/hip_runtime.h>
#include <hip/hip_bf16.h>
#include <stdint.h>

#define I_DIM 2048
#define O_DIM 8192
#define T_TOK 512
#define NSTR  64
#define BK    64
#define NSTEP (I_DIM / BK)

#define TILE_B 16384  // bytes per (stripe,step): B-hi only, pre-swizzled LDS image

// gemm11 LDS: A 8KB (32 rows x 128B, hi+lo) + B-hi dbuf 2x16KB = 40KB -> 4 blocks/CU
#define A_HI 0
#define A_LO 4096
#define B0_OFF 8192
#define SMEM11 40960

// workspace layout
#define WT_OFF   ((size_t)0)             // 32MB weight hi-tiles
#define XC_OFF   ((size_t)67108864)      // 4MB xc f32
#define THR_OFF  ((size_t)71303168)      // 512KB thrs f32[64][2048]
#define PM_OFF   ((size_t)71827456)      // 2MB pm_part f32[64][8192]
#define PMB_OFF  ((size_t)73924608)      // 32KB pmb f32[8192]
#define CNT_OFF  ((size_t)73957376)      // 2KB counts i32[512]

typedef __attribute__((ext_vector_type(8))) short bf16x8;
typedef __attribute__((ext_vector_type(4))) float f32x4;
typedef __attribute__((ext_vector_type(4))) int i32x4;

__device__ __forceinline__ void gload16(const void* g, void* l) {
  __builtin_amdgcn_global_load_lds(
      (const __attribute__((address_space(1))) void*)g,
      (__attribute__((address_space(3))) void*)l, 16, 0, 0);
}

// k0: fused prep: xc = x - mu; thrs = thresholds*std; zero counts.
__global__ void cwic_prep(const float* __restrict__ x, const float* __restrict__ mu,
                          const float* __restrict__ thresholds,
                          const float* __restrict__ stdv, float* __restrict__ xc,
                          float* __restrict__ thrs, int* __restrict__ counts) {
  int idx = blockIdx.x * 256 + threadIdx.x;  // 262144 float4s of xc
  float4 xv = ((const float4*)x)[idx];
  float4 mv = ((const float4*)mu)[idx & 511];
  float4 r;
  r.x = xv.x - mv.x; r.y = xv.y - mv.y; r.z = xv.z - mv.z; r.w = xv.w - mv.w;
  ((float4*)xc)[idx] = r;
  if (idx < (NSTR * I_DIM) / 4) {  // 32768 float4s of thrs
    float4 t = ((const float4*)thresholds)[idx];
    float4 s = ((const float4*)stdv)[idx & 511];
    float4 ts;
    ts.x = t.x * s.x; ts.y = t.y * s.y; ts.z = t.z * s.z; ts.w = t.w * s.w;
    ((float4*)thrs)[idx] = ts;
  }
  if (idx < T_TOK) counts[idx] = 0;
}

// k1: weight hi-split f32 -> bf16 RNE tiles (pre-swizzled LDS image) + post_mu
// partials. 2-product scheme: y ~= (A_hi + A_lo) * B_hi.
__global__ __launch_bounds__(256) void cwic_wprep(const float* __restrict__ w,
                                                  const float* __restrict__ mu,
                                                  char* __restrict__ wt,
                                                  float* __restrict__ pm_part) {
  const int bp = blockIdx.x;  // 2048 = 64 stripes x 32 steps
  const int n = bp >> 5, step = bp & 31;
  const int tid = threadIdx.x;
  const int o = tid & 127, kh = tid >> 7;
  const float* wp = w + (size_t)(step * BK + kh * 32) * O_DIM + n * 128 + o;
  char* tb = wt + (size_t)bp * TILE_B;
  const int rowb = o * 128;
  const int swz = (o & 7) << 4;
  float pm = 0.0f;
  #pragma unroll
  for (int g = 0; g < 4; ++g) {
    unsigned hv[4];
    unsigned hprev = 0;
    #pragma unroll
    for (int e = 0; e < 8; ++e) {
      const int irow = step * BK + kh * 32 + g * 8 + e;
      float v = wp[(size_t)(g * 8 + e) * O_DIM];
      pm += mu[irow] * v;
      unsigned u = __builtin_bit_cast(unsigned, v);
      unsigned r = u + 0x7fffu + ((u >> 16) & 1u);   // RNE to bf16
      unsigned short h = (unsigned short)(r >> 16);
      if ((e & 1) == 0) hprev = h;
      else hv[e >> 1] = hprev | (((unsigned)h) << 16);
    }
    *(i32x4*)(tb + rowb + ((kh * 64 + g * 16) ^ swz)) = *(i32x4*)hv;
  }
  pm_part[(size_t)(step * 2 + kh) * O_DIM + n * 128 + o] = pm;
}

// k2: pmb[o] = bias[o] + sum_s pm_part[s][o] (fixed order, deterministic)
__global__ void cwic_pmb(const float* __restrict__ pm_part,
                         const float* __restrict__ bias, float* __restrict__ pmb) {
  int o = blockIdx.x * 256 + threadIdx.x;
  float s = bias[o];
  #pragma unroll 8
  for (int j = 0; j < 64; ++j) s += pm_part[(size_t)j * O_DIM + o];
  pmb[o] = s;
}

// k3: masked GEMM, T3/T4 schedule. Block = 32 tokens x 128 outputs, 4 waves 2x2.
// B-hi double-buffered: B(i+1) issued a full step ahead; barrier1 waits only
// vmcnt(12) (= 8 x/thr prefetch + 4 B(i+1) gloads stay in flight) + lgkmcnt(0)
// for the A-writes — never vmcnt(0) in the loop. Barrier2 is a bare s_barrier
// (WAR fence for the single A buffer). 40KB LDS -> 4 blocks/CU = grid/CU.
__global__ __launch_bounds__(256, 4) void cwic_gemm11(
    const float* __restrict__ xc, const char* __restrict__ wt,
    const float* __restrict__ thrs, const float* __restrict__ pmb,
    float* __restrict__ y, int* __restrict__ counts) {
  extern __shared__ char smem[];
  const int b = blockIdx.x;
  // XCD swizzle: all 16 token-tiles of one stripe land on one XCD -> B L2-hot.
  const int nid = (b & 7) * 128 + (b >> 3);
  const int n = nid >> 4, th = nid & 15;
  const int trow0 = th * 32, ocol0 = n * 128;
  const int tid = threadIdx.x;
  const int lane = tid & 63, wid = tid >> 6;
  const int wr = wid >> 1, wc = wid & 1;
  const int l15 = lane & 15, l4 = lane >> 4;

  const int t_loc = tid >> 3, kq = tid & 7;  // A staging: token row (0..31), k-octet
  const float* xrow = xc + (size_t)(trow0 + t_loc) * I_DIM + kq * 8;
  const float* thg = thrs + (size_t)n * I_DIM + kq * 8;
  const char* wtb = wt + (size_t)(n * NSTEP) * TILE_B;

  f32x4 acc[4];
  #pragma unroll
  for (int ni = 0; ni < 4; ++ni) acc[ni] = (f32x4)(0.0f);

  float4 xA0, xA1, tA0, tA1;  // current-step prefetch regs (static names)
  float4 xB0, xB1, tB0, tB1;  // next-step prefetch regs
  int cnt = 0;

  // ---- prologue: x/thr(0) regs; B(0) -> buf0; one-time full drain ----
  xA0 = *(const float4*)(xrow);
  xA1 = *(const float4*)(xrow + 4);
  tA0 = *(const float4*)(thg);
  tA1 = *(const float4*)(thg + 4);
  {
    const char* bs = wtb + tid * 16;
    #pragma unroll
    for (int j = 0; j < 4; ++j)
      gload16(bs + j * 4096, smem + B0_OFF + j * 4096 + tid * 16);
  }
  __syncthreads();

#define STEP11(STEP_I, CUR, XC0, XC1, TC0, TC1, XN0, XN1, TN0, TN1)            \
  {                                                                            \
    const int step_ = (STEP_I);                                                \
    const int s1_ = (step_ + 1 < NSTEP) ? step_ + 1 : step_;                   \
    /* (1) prefetch x/thr(step+1) into the OTHER static regs (8 vmem) */       \
    XN0 = *(const float4*)(xrow + s1_ * BK);                                   \
    XN1 = *(const float4*)(xrow + s1_ * BK + 4);                               \
    TN0 = *(const float4*)(thg + s1_ * BK);                                    \
    TN1 = *(const float4*)(thg + s1_ * BK + 4);                                \
    /* (2) issue B(step+1) -> buf[CUR^1] (4 vmem) */                           \
    {                                                                          \
      const char* bs_ = wtb + (size_t)s1_ * TILE_B + tid * 16;                 \
      char* bd_ = smem + B0_OFF + ((CUR) ^ 1) * 16384 + tid * 16;              \
      _Pragma("unroll") for (int j_ = 0; j_ < 4; ++j_)                         \
        gload16(bs_ + j_ * 4096, bd_ + j_ * 4096);                             \
    }                                                                          \
    /* (3) A-build(step): mask+count + hi/lo split via RNE bf16 casts */       \
    {                                                                          \
      const float xs_[8] = {XC0.x, XC0.y, XC0.z, XC0.w, XC1.x, XC1.y, XC1.z, XC1.w}; \
      const float ts_[8] = {TC0.x, TC0.y, TC0.z, TC0.w, TC1.x, TC1.y, TC1.z, TC1.w}; \
      bf16x8 hv8_, lv8_;                                                       \
      _Pragma("unroll") for (int e_ = 0; e_ < 8; ++e_) {                       \
        bool keep_ = fabsf(xs_[e_]) > ts_[e_];                                 \
        cnt += keep_ ? 1 : 0;                                                  \
        float a_ = keep_ ? xs_[e_] : 0.0f;                                     \
        __hip_bfloat16 h_ = __float2bfloat16(a_);                              \
        float hf_ = __bfloat162float(h_);                                      \
        __hip_bfloat16 l_ = __float2bfloat16(a_ - hf_);                        \
        hv8_[e_] = __builtin_bit_cast(short, h_);                              \
        lv8_[e_] = __builtin_bit_cast(short, l_);                              \
      }                                                                        \
      const int ad_ = t_loc * 128 + ((kq * 16) ^ ((t_loc & 7) << 4));          \
      *(bf16x8*)(smem + A_HI + ad_) = hv8_;                                    \
      *(bf16x8*)(smem + A_LO + ad_) = lv8_;                                    \
    }                                                                          \
    /* (4) barrier1: drain B(step) DMA (12 newer stay in flight) + A-writes */ \
    asm volatile("s_waitcnt vmcnt(12) lgkmcnt(0)" ::: "memory");               \
    __builtin_amdgcn_sched_barrier(0);                                         \
    __builtin_amdgcn_s_barrier();                                              \
    __builtin_amdgcn_sched_barrier(0);                                         \
    /* (5) MFMA(step) from A + buf[CUR] */                                     \
    __builtin_amdgcn_s_setprio(1);                                             \
    _Pragma("unroll") for (int s32_ = 0; s32_ < 2; ++s32_) {                   \
      const int r_ = wr * 16 + l15;                                            \
      const int ada_ = r_ * 128 + (((s32_ * 64) + l4 * 16) ^ ((r_ & 7) << 4)); \
      bf16x8 afh_ = *(const bf16x8*)(smem + A_HI + ada_);                      \
      bf16x8 afl_ = *(const bf16x8*)(smem + A_LO + ada_);                      \
      _Pragma("unroll") for (int ni_ = 0; ni_ < 4; ++ni_) {                    \
        const int o_ = wc * 64 + ni_ * 16 + l15;                               \
        const int adb_ = o_ * 128 + (((s32_ * 64) + l4 * 16) ^ ((o_ & 7) << 4)); \
        bf16x8 bh_ = *(const bf16x8*)(smem + B0_OFF + (CUR) * 16384 + adb_);   \
        acc[ni_] = __builtin_amdgcn_mfma_f32_16x16x32_bf16(afh_, bh_, acc[ni_], 0, 0, 0); \
        acc[ni_] = __builtin_amdgcn_mfma_f32_16x16x32_bf16(afl_, bh_, acc[ni_], 0, 0, 0); \
      }                                                                        \
    }                                                                          \
    __builtin_amdgcn_s_setprio(0);                                             \
    /* (6) barrier2: WAR fence for A (no memory drain) */                      \
    __builtin_amdgcn_sched_barrier(0);                                         \
    __builtin_amdgcn_s_barrier();                                              \
    __builtin_amdgcn_sched_barrier(0);                                         \
  }

  for (int sp = 0; sp < NSTEP; sp += 2) {
    STEP11(sp,     0, xA0, xA1, tA0, tA1, xB0, xB1, tB0, tB1);
    STEP11(sp + 1, 1, xB0, xB1, tB0, tB1, xA0, xA1, tA0, tA1);
  }
#undef STEP11

  // ---- mask-count reduce: 8 threads (kq) share one token row ----
  cnt += __shfl_xor(cnt, 1);
  cnt += __shfl_xor(cnt, 2);
  cnt += __shfl_xor(cnt, 4);
  if (kq == 0) atomicAdd(&counts[trow0 + t_loc], cnt);

  // ---- epilogue: y = acc + (post_mu + bias); C/D layout m89-verified ----
  #pragma unroll
  for (int ni = 0; ni < 4; ++ni) {
    const int o = ocol0 + wc * 64 + ni * 16 + l15;
    const float pv = pmb[o];
    const int row0 = trow0 + wr * 16 + l4 * 4;
    #pragma unroll
    for (int r = 0; r < 4; ++r) {
      y[(size_t)(row0 + r) * O_DIM + o] = acc[ni][r] + pv;
    }
  }
}

// k4: flops outputs. flops_sparse = 16777216 * cnt/(64*2048) = 128*cnt (exact).
__global__ void cwic_fin(const int* __restrict__ counts, float* __restrict__ outF) {
  int t = blockIdx.x * 256 + threadIdx.x;
  outF[t] = 16777216.0f;
  outF[T_TOK + t] = 128.0f * (float)counts[t];
}

extern "C" void kernel_launch(void* const* d_in, const int* in_sizes, int n_in,
                              void* d_out, int out_size, void* d_ws, size_t ws_size,
                              hipStream_t stream) {
  const float* x = (const float*)d_in[0];
  const float* w = (const float*)d_in[1];
  const float* bias = (const float*)d_in[2];
  const float* thresholds = (const float*)d_in[3];
  const float* mu = (const float*)d_in[4];
  const float* stdv = (const float*)d_in[5];
  float* y = (float*)d_out;

  char* ws = (char*)d_ws;
  char* wt = ws + WT_OFF;
  float* xc = (float*)(ws + XC_OFF);
  float* thrs = (float*)(ws + THR_OFF);
  float* pm_part = (float*)(ws + PM_OFF);
  float* pmb = (float*)(ws + PMB_OFF);
  int* counts = (int*)(ws + CNT_OFF);

  cwic_prep<<<1024, 256, 0, stream>>>(x, mu, thresholds, stdv, xc, thrs, counts);
  cwic_wprep<<<NSTR * NSTEP, 256, 0, stream>>>(w, mu, wt, pm_part);
  cwic_pmb<<<32, 256, 0, stream>>>(pm_part, bias, pmb);
  cwic_gemm11<<<1024, 256, SMEM11, stream>>>(xc, wt, thrs, pmb, y, counts);
  cwic_fin<<<2, 256, 0, stream>>>(counts, y + (size_t)T_TOK * O_DIM);
}

// Round 16
// 75.785 us; speedup vs baseline: 1.1758x; 1.1758x over previous
//
#include <hip/hip_runtime.h>
#include <hip/hip_bf16.h>
#include <stdint.h>

#define I_DIM 2048
#define O_DIM 8192
#define T_TOK 512
#define NSTR  64
#define BK    64
#define NSTEP (I_DIM / BK)

#define TILE_B 16384  // bytes per (stripe,step): B-hi, FRAGMENT-MAJOR layout:
                      // frag_id = s32*8 + (o/16); within frag: lane*16 bytes,
                      // lane = (o&15) + (k%32/8)*16, 8 bf16 = k0..k0+7 of col o.

// gemm12 LDS: A dbuf 2 x (hi 8K + lo 8K) = 32KB, thr 8KB @ 32768 -> 40KB
#define THR_S 32768
#define SMEM12 40960

// workspace layout
#define WT_OFF   ((size_t)0)             // 32MB weight hi-tiles (fragment-major)
#define XC_OFF   ((size_t)67108864)      // 4MB xc f32
#define THR_OFF  ((size_t)71303168)      // 512KB thrs f32[64][2048]
#define PM_OFF   ((size_t)71827456)      // 2MB pm_part f32[64][8192]
#define PMB_OFF  ((size_t)73924608)      // 32KB pmb f32[8192]
#define CNT_OFF  ((size_t)73957376)      // 2KB counts i32[512]

typedef __attribute__((ext_vector_type(8))) short bf16x8;
typedef __attribute__((ext_vector_type(4))) float f32x4;
typedef __attribute__((ext_vector_type(4))) int i32x4;

// k0: fused prep: xc = x - mu; thrs = thresholds*std; zero counts.
__global__ void cwic_prep(const float* __restrict__ x, const float* __restrict__ mu,
                          const float* __restrict__ thresholds,
                          const float* __restrict__ stdv, float* __restrict__ xc,
                          float* __restrict__ thrs, int* __restrict__ counts) {
  int idx = blockIdx.x * 256 + threadIdx.x;  // 262144 float4s of xc
  float4 xv = ((const float4*)x)[idx];
  float4 mv = ((const float4*)mu)[idx & 511];
  float4 r;
  r.x = xv.x - mv.x; r.y = xv.y - mv.y; r.z = xv.z - mv.z; r.w = xv.w - mv.w;
  ((float4*)xc)[idx] = r;
  if (idx < (NSTR * I_DIM) / 4) {  // 32768 float4s of thrs
    float4 t = ((const float4*)thresholds)[idx];
    float4 s = ((const float4*)stdv)[idx & 511];
    float4 ts;
    ts.x = t.x * s.x; ts.y = t.y * s.y; ts.z = t.z * s.z; ts.w = t.w * s.w;
    ((float4*)thrs)[idx] = ts;
  }
  if (idx < T_TOK) counts[idx] = 0;
}

// k1: weight hi-split f32 -> bf16 RNE, written FRAGMENT-MAJOR so the GEMM reads
// each MFMA B-fragment as one coalesced 1KB wave-load straight to registers.
__global__ __launch_bounds__(256) void cwic_wprep(const float* __restrict__ w,
                                                  const float* __restrict__ mu,
                                                  char* __restrict__ wt,
                                                  float* __restrict__ pm_part) {
  const int bp = blockIdx.x;  // 2048 = 64 stripes x 32 steps
  const int n = bp >> 5, step = bp & 31;
  const int tid = threadIdx.x;
  const int o = tid & 127, kh = tid >> 7;
  const float* wp = w + (size_t)(step * BK + kh * 32) * O_DIM + n * 128 + o;
  char* tb = wt + (size_t)bp * TILE_B;
  float pm = 0.0f;
  #pragma unroll
  for (int g = 0; g < 4; ++g) {
    unsigned hv[4];
    unsigned hprev = 0;
    #pragma unroll
    for (int e = 0; e < 8; ++e) {
      const int irow = step * BK + kh * 32 + g * 8 + e;
      float v = wp[(size_t)(g * 8 + e) * O_DIM];
      pm += mu[irow] * v;
      unsigned u = __builtin_bit_cast(unsigned, v);
      unsigned r = u + 0x7fffu + ((u >> 16) & 1u);   // RNE to bf16
      unsigned short h = (unsigned short)(r >> 16);
      if ((e & 1) == 0) hprev = h;
      else hv[e >> 1] = hprev | (((unsigned)h) << 16);
    }
    // fragment-major: frag (kh*8 + o/16), lane (o&15) + g*16
    const int off = (kh * 8 + (o >> 4)) * 1024 + (((o & 15) + g * 16) * 16);
    *(i32x4*)(tb + off) = *(i32x4*)hv;
  }
  pm_part[(size_t)(step * 2 + kh) * O_DIM + n * 128 + o] = pm;
}

// k2: pmb[o] = bias[o] + sum_s pm_part[s][o] (fixed order, deterministic)
__global__ void cwic_pmb(const float* __restrict__ pm_part,
                         const float* __restrict__ bias, float* __restrict__ pmb) {
  int o = blockIdx.x * 256 + threadIdx.x;
  float s = bias[o];
  #pragma unroll 8
  for (int j = 0; j < 64; ++j) s += pm_part[(size_t)j * O_DIM + o];
  pmb[o] = s;
}

// k3: masked GEMM "B-direct". Block = 64 tokens x 128 cols, 4 waves 2x2 (wave
// 32x64), grid 512, 2-product. B fragments load straight from fragment-major
// global tiles into registers (no B LDS, no DMA). A (hi/lo) double-buffered in
// LDS -> ONE __syncthreads per step (A-dbuf WAR-safe: reads are consumed by
// MFMA before the next barrier). thr staged once in LDS. LDS demand ~halved vs
// R13-R15 (the measured binding resource).
__global__ __launch_bounds__(256, 2) void cwic_gemm12(
    const float* __restrict__ xc, const char* __restrict__ wt,
    const float* __restrict__ thrs, const float* __restrict__ pmb,
    float* __restrict__ y, int* __restrict__ counts) {
  extern __shared__ char smem[];
  const int b = blockIdx.x;
  // XCD swizzle: the 8 token-tiles of one stripe share an XCD -> tiles L2-hot.
  const int nid = (b & 7) * 64 + (b >> 3);
  const int n = nid >> 3, tt = nid & 7;
  const int trow0 = tt * 64, ocol0 = n * 128;
  const int tid = threadIdx.x;
  const int lane = tid & 63, wid = tid >> 6;
  const int wr = wid >> 1, wc = wid & 1;
  const int l15 = lane & 15, l4 = lane >> 4;
  const int t_loc = tid >> 2, kq = tid & 3;  // A staging: token row (0..63), k-16-chunk

  // ---- prologue: stage thr (8KB) into LDS ----
  float* thr_s = (float*)(smem + THR_S);
  {
    const float4* src = (const float4*)(thrs + (size_t)n * I_DIM);
    ((float4*)thr_s)[tid] = src[tid];
    ((float4*)thr_s)[tid + 256] = src[tid + 256];
  }
  __syncthreads();

  const float* xrow = xc + (size_t)(trow0 + t_loc) * I_DIM + kq * 16;
  // wave's fragment base: col-group wc*4 folded in; lane*16 is the coalesced lane slot
  const char* wfrag = wt + (size_t)(n * NSTEP) * TILE_B + (wc * 4) * 1024 + lane * 16;

  f32x4 acc[2][4];
  #pragma unroll
  for (int mi = 0; mi < 2; ++mi)
    #pragma unroll
    for (int ni = 0; ni < 4; ++ni) acc[mi][ni] = (f32x4)(0.0f);
  int cnt = 0;

  for (int step = 0; step < NSTEP; ++step) {
    const int abase = (step & 1) * 16384;  // A double-buffer (LDS addr, not reg idx)
    // (1) B fragments for THIS step -> regs (coalesced 1KB wave-loads, L2-hot)
    bf16x8 bfr[8];  // [s32*4 + ni], constant-indexed (no rule-#20 scratch)
    {
      const char* bp_ = wfrag + (size_t)step * TILE_B;
      #pragma unroll
      for (int f = 0; f < 8; ++f)
        bfr[f] = *(const bf16x8*)(bp_ + (((f >> 2) * 8) + (f & 3)) * 1024);
    }
    // (2) x for THIS step + thr from LDS
    float4 xv[4], tv[4];
    #pragma unroll
    for (int q = 0; q < 4; ++q) {
      xv[q] = *(const float4*)(xrow + step * BK + q * 4);
      tv[q] = *(const float4*)(thr_s + step * BK + kq * 16 + q * 4);
    }
    // (3) A-build: mask+count + hi/lo split via RNE bf16 casts (verified bits)
    {
      const float xs[16] = {xv[0].x, xv[0].y, xv[0].z, xv[0].w,
                            xv[1].x, xv[1].y, xv[1].z, xv[1].w,
                            xv[2].x, xv[2].y, xv[2].z, xv[2].w,
                            xv[3].x, xv[3].y, xv[3].z, xv[3].w};
      const float ts[16] = {tv[0].x, tv[0].y, tv[0].z, tv[0].w,
                            tv[1].x, tv[1].y, tv[1].z, tv[1].w,
                            tv[2].x, tv[2].y, tv[2].z, tv[2].w,
                            tv[3].x, tv[3].y, tv[3].z, tv[3].w};
      const int rowb = t_loc * 128;
      const int swz = (t_loc & 7) << 4;
      #pragma unroll
      for (int g = 0; g < 2; ++g) {
        bf16x8 hv8, lv8;
        #pragma unroll
        for (int e = 0; e < 8; ++e) {
          const float xvv = xs[g * 8 + e], tvv = ts[g * 8 + e];
          bool keep = fabsf(xvv) > tvv;
          cnt += keep ? 1 : 0;
          float a = keep ? xvv : 0.0f;
          __hip_bfloat16 h = __float2bfloat16(a);
          float hf = __bfloat162float(h);
          __hip_bfloat16 l = __float2bfloat16(a - hf);
          hv8[e] = __builtin_bit_cast(short, h);
          lv8[e] = __builtin_bit_cast(short, l);
        }
        const int ad = rowb + (((kq * 32) + g * 16) ^ swz);
        *(bf16x8*)(smem + abase + ad) = hv8;
        *(bf16x8*)(smem + abase + 8192 + ad) = lv8;
      }
    }
    __syncthreads();  // A[abase] writes visible; also drains B/x loads (needed now)
    // (4) MFMA: A from LDS, B from regs
    __builtin_amdgcn_s_setprio(1);
    #pragma unroll
    for (int s32 = 0; s32 < 2; ++s32) {
      bf16x8 afh[2], afl[2];
      #pragma unroll
      for (int mi = 0; mi < 2; ++mi) {
        const int r = wr * 32 + mi * 16 + l15;
        const int ada = r * 128 + (((s32 * 64) + l4 * 16) ^ ((r & 7) << 4));
        afh[mi] = *(const bf16x8*)(smem + abase + ada);
        afl[mi] = *(const bf16x8*)(smem + abase + 8192 + ada);
      }
      #pragma unroll
      for (int ni = 0; ni < 4; ++ni) {
        bf16x8 bh = bfr[s32 * 4 + ni];
        #pragma unroll
        for (int mi = 0; mi < 2; ++mi) {
          acc[mi][ni] = __builtin_amdgcn_mfma_f32_16x16x32_bf16(afh[mi], bh, acc[mi][ni], 0, 0, 0);
          acc[mi][ni] = __builtin_amdgcn_mfma_f32_16x16x32_bf16(afl[mi], bh, acc[mi][ni], 0, 0, 0);
        }
      }
    }
    __builtin_amdgcn_s_setprio(0);
    // no second barrier: next step writes the OTHER A buffer (dbuf WAR-safe)
  }

  // ---- mask-count reduce: 4 threads (kq) share one token row ----
  cnt += __shfl_xor(cnt, 1);
  cnt += __shfl_xor(cnt, 2);
  if (kq == 0) atomicAdd(&counts[trow0 + t_loc], cnt);

  // ---- epilogue: y = acc + (post_mu + bias); C/D layout m89-verified ----
  #pragma unroll
  for (int ni = 0; ni < 4; ++ni) {
    const int o = ocol0 + wc * 64 + ni * 16 + l15;
    const float pv = pmb[o];
    #pragma unroll
    for (int mi = 0; mi < 2; ++mi) {
      const int row0 = trow0 + wr * 32 + mi * 16 + l4 * 4;
      #pragma unroll
      for (int r = 0; r < 4; ++r) {
        y[(size_t)(row0 + r) * O_DIM + o] = acc[mi][ni][r] + pv;
      }
    }
  }
}

// k4: flops outputs. flops_sparse = 16777216 * cnt/(64*2048) = 128*cnt (exact).
__global__ void cwic_fin(const int* __restrict__ counts, float* __restrict__ outF) {
  int t = blockIdx.x * 256 + threadIdx.x;
  outF[t] = 16777216.0f;
  outF[T_TOK + t] = 128.0f * (float)counts[t];
}

extern "C" void kernel_launch(void* const* d_in, const int* in_sizes, int n_in,
                              void* d_out, int out_size, void* d_ws, size_t ws_size,
                              hipStream_t stream) {
  const float* x = (const float*)d_in[0];
  const float* w = (const float*)d_in[1];
  const float* bias = (const float*)d_in[2];
  const float* thresholds = (const float*)d_in[3];
  const float* mu = (const float*)d_in[4];
  const float* stdv = (const float*)d_in[5];
  float* y = (float*)d_out;

  char* ws = (char*)d_ws;
  char* wt = ws + WT_OFF;
  float* xc = (float*)(ws + XC_OFF);
  float* thrs = (float*)(ws + THR_OFF);
  float* pm_part = (float*)(ws + PM_OFF);
  float* pmb = (float*)(ws + PMB_OFF);
  int* counts = (int*)(ws + CNT_OFF);

  cwic_prep<<<1024, 256, 0, stream>>>(x, mu, thresholds, stdv, xc, thrs, counts);
  cwic_wprep<<<NSTR * NSTEP, 256, 0, stream>>>(w, mu, wt, pm_part);
  cwic_pmb<<<32, 256, 0, stream>>>(pm_part, bias, pmb);
  cwic_gemm12<<<512, 256, SMEM12, stream>>>(xc, wt, thrs, pmb, y, counts);
  cwic_fin<<<2, 256, 0, stream>>>(counts, y + (size_t)T_TOK * O_DIM);
}